// Round 1
// baseline (159.008 us; speedup 1.0000x reference)
//
#include <hip/hip_runtime.h>

#define COLS 2048
#define KSEL 256
#define TPB  256
#define EPT  8          // COLS / TPB
#define NREP 8          // histogram replicas (salted by tid&7)

// One block per row. Exact top-K selection via 4-pass 8-bit radix select on
// score bit patterns (scores are non-negative floats -> uint order monotone).
// Tie handling matches jax.lax.top_k (lower index first).
__global__ __launch_bounds__(TPB)
void CompetitiveSelection_topk_kernel(const float* __restrict__ x,
                                      const float* __restrict__ imp,
                                      float* __restrict__ out)
{
    const int row = blockIdx.x;
    const int tid = threadIdx.x;
    const long base = (long)row * COLS + (long)tid * EPT;

    __shared__ unsigned int hist[256][NREP];   // 8 KiB, bin-major so replicas hit distinct banks
    __shared__ unsigned int tcnt[TPB];         // per-thread equal-count / scan bases
    __shared__ unsigned int bc[2];             // broadcast: T bits, kk

    // ---- load 8 contiguous x + importance values per thread ----
    float4 xa = *(const float4*)(x + base);
    float4 xb = *(const float4*)(x + base + 4);
    float4 ia = *(const float4*)(imp + tid * EPT);
    float4 ib = *(const float4*)(imp + tid * EPT + 4);

    float xv[EPT] = {xa.x, xa.y, xa.z, xa.w, xb.x, xb.y, xb.z, xb.w};
    float iv[EPT] = {ia.x, ia.y, ia.z, ia.w, ib.x, ib.y, ib.z, ib.w};

    unsigned int sc[EPT];
#pragma unroll
    for (int i = 0; i < EPT; ++i)
        sc[i] = __float_as_uint(fabsf(xv[i]) * fabsf(iv[i]));

    unsigned int T  = 0;      // determined high bits of k-th value (low bits 0)
    unsigned int kk = KSEL;   // how many still needed from the active set
    const int rep = tid & (NREP - 1);

    for (int p = 0; p < 4; ++p) {
        const int shift = 24 - 8 * p;
        const unsigned int highmask = (p == 0) ? 0u : (0xFFFFFFFFu << (32 - 8 * p));

        // zero histogram (each thread clears one bin's 8 replicas = 32B)
        *(uint4*)&hist[tid][0] = make_uint4(0, 0, 0, 0);
        *(uint4*)&hist[tid][4] = make_uint4(0, 0, 0, 0);
        __syncthreads();

#pragma unroll
        for (int i = 0; i < EPT; ++i) {
            if ((sc[i] & highmask) == T)
                atomicAdd(&hist[(sc[i] >> shift) & 255][rep], 1u);
        }
        __syncthreads();

        // wave 0: sum replicas, suffix-scan, find the bin containing rank kk
        if (tid < 64) {
            unsigned int cnt[4];
#pragma unroll
            for (int b = 0; b < 4; ++b) {
                uint4 h0 = *(const uint4*)&hist[4 * tid + b][0];
                uint4 h1 = *(const uint4*)&hist[4 * tid + b][4];
                cnt[b] = h0.x + h0.y + h0.z + h0.w + h1.x + h1.y + h1.z + h1.w;
            }
            unsigned int tot = cnt[0] + cnt[1] + cnt[2] + cnt[3];
            // inclusive suffix-sum across lanes: S = sum of tot over lanes >= tid
            unsigned int S = tot;
#pragma unroll
            for (int off = 1; off < 64; off <<= 1) {
                unsigned int u = __shfl_down(S, off);
                if (tid + off < 64) S += u;
            }
            unsigned int above = S - tot;   // count in bins >= 4*(tid+1)
            int c = -1;
            unsigned int cab = 0;
#pragma unroll
            for (int b = 3; b >= 0; --b) {
                if (c < 0 && above < kk && above + cnt[b] >= kk) {
                    c = 4 * tid + b;
                    cab = above;
                }
                above += cnt[b];
            }
            if (c >= 0) {   // exactly one lane finds the crossing bin
                bc[0] = T | ((unsigned int)c << shift);
                bc[1] = kk - cab;
            }
        }
        __syncthreads();
        T  = bc[0];
        kk = bc[1];
        // bc is rewritten only after next pass's two barriers -> no extra sync needed
    }

    // T = exact k-th largest score bits; kk = #(==T) elements to keep (lowest index first)
    unsigned int myeq = 0;
    bool isel[EPT];
#pragma unroll
    for (int i = 0; i < EPT; ++i) {
        isel[i] = sc[i] > T;
        myeq += (sc[i] == T) ? 1u : 0u;
    }
    tcnt[tid] = myeq;
    __syncthreads();

    // index-ordered exclusive scan of equal-counts (wave 0, shuffles)
    if (tid < 64) {
        uint4 v = *(const uint4*)&tcnt[4 * tid];
        unsigned int tot = v.x + v.y + v.z + v.w;
        unsigned int S = tot;
#pragma unroll
        for (int off = 1; off < 64; off <<= 1) {
            unsigned int u = __shfl_up(S, off);
            if (tid >= off) S += u;
        }
        unsigned int excl = S - tot;
        uint4 o;
        o.x = excl;
        o.y = o.x + v.x;
        o.z = o.y + v.y;
        o.w = o.z + v.z;
        *(uint4*)&tcnt[4 * tid] = o;
    }
    __syncthreads();
    unsigned int ebase = tcnt[tid];

    float ov[EPT];
#pragma unroll
    for (int i = 0; i < EPT; ++i) {
        bool pick = isel[i];
        if (sc[i] == T) { pick = (ebase < kk); ebase += 1; }
        ov[i] = pick ? xv[i] : 0.0f;
    }
    *(float4*)(out + base)     = make_float4(ov[0], ov[1], ov[2], ov[3]);
    *(float4*)(out + base + 4) = make_float4(ov[4], ov[5], ov[6], ov[7]);
}

extern "C" void kernel_launch(void* const* d_in, const int* in_sizes, int n_in,
                              void* d_out, int out_size, void* d_ws, size_t ws_size,
                              hipStream_t stream)
{
    const float* x   = (const float*)d_in[0];
    const float* imp = (const float*)d_in[1];
    float* out       = (float*)d_out;

    const int rows = in_sizes[0] / COLS;   // 32768
    CompetitiveSelection_topk_kernel<<<dim3(rows), dim3(TPB), 0, stream>>>(x, imp, out);
}

// Round 2
// 108.466 us; speedup vs baseline: 1.4660x; 1.4660x over previous
//
#include <hip/hip_runtime.h>

#define COLS 2048
#define KSEL 256
#define TPB  256
#define EPT  8          // COLS / TPB

// One block per row. Exact top-K via 4-pass radix select on score bit patterns
// (scores non-negative -> uint order monotone; bit31 always 0).
// Digits: P1 bits[30:23] (8b, 8 replicas), P2 bits[22:15] (8b, 2 replicas),
//         P3 bits[14:7]  (8b, 1 copy),     P4 bits[6:0]   (7b, 1 copy).
// All LDS access patterns are <=2-way bank aliased (odd strides / unit stride).
// Tie handling matches jax.lax.top_k (lower index first).
__global__ __launch_bounds__(TPB)
void CompetitiveSelection_topk_kernel(const float* __restrict__ x,
                                      const float* __restrict__ imp,
                                      float* __restrict__ out)
{
    const int row = blockIdx.x;
    const int tid = threadIdx.x;
    const long base = (long)row * COLS + (long)tid * EPT;

    __shared__ __align__(16) unsigned int hist[2304]; // P1 [256][9]; P2 [256][3]; P3/P4 [256]
    __shared__ __align__(16) unsigned int bsum[256];
    __shared__ __align__(16) unsigned int tcnt[256];
    __shared__ unsigned int bc[2];                    // broadcast: T bits, kk

    // ---- load 8 contiguous x + importance values per thread ----
    float4 xa = *(const float4*)(x + base);
    float4 xb = *(const float4*)(x + base + 4);
    float4 ia = *(const float4*)(imp + tid * EPT);
    float4 ib = *(const float4*)(imp + tid * EPT + 4);

    float xv[EPT] = {xa.x, xa.y, xa.z, xa.w, xb.x, xb.y, xb.z, xb.w};
    float iv[EPT] = {ia.x, ia.y, ia.z, ia.w, ib.x, ib.y, ib.z, ib.w};

    unsigned int sc[EPT];
#pragma unroll
    for (int i = 0; i < EPT; ++i)
        sc[i] = __float_as_uint(fabsf(xv[i]) * fabsf(iv[i]));

    unsigned int T  = 0;      // determined high bits of k-th key (low bits 0)
    unsigned int kk = KSEL;   // rank still needed within active set

    // wave0: suffix-scan 256 counts, find crossing bin for rank curkk.
    // Writes bc[0] = curT | (c << shift), bc[1] = curkk - count_above_bin.
    auto scan256 = [&](const unsigned int* cnts, unsigned int curT, int shift,
                       unsigned int curkk) {
        if (tid < 64) {
            uint4 v = *(const uint4*)&cnts[4 * tid];
            unsigned int cnt[4] = {v.x, v.y, v.z, v.w};
            unsigned int tot = v.x + v.y + v.z + v.w;
            unsigned int S = tot;   // inclusive suffix sum over lanes >= tid
#pragma unroll
            for (int off = 1; off < 64; off <<= 1) {
                unsigned int u = __shfl_down(S, off);
                if (tid + off < 64) S += u;
            }
            unsigned int above = S - tot;  // count in bins >= 4*(tid+1)
            int c = -1;
            unsigned int cab = 0;
#pragma unroll
            for (int b = 3; b >= 0; --b) {
                if (c < 0 && above < curkk && above + cnt[b] >= curkk) {
                    c = 4 * tid + b;
                    cab = above;
                }
                above += cnt[b];
            }
            if (c >= 0) {   // exactly one lane
                bc[0] = curT | ((unsigned int)c << shift);
                bc[1] = curkk - cab;
            }
        }
    };

    // =================== PASS 1: bits [30:23], 8 replicas ===================
    {
#pragma unroll
        for (int k = 0; k < 9; ++k) hist[tid + 256 * k] = 0;   // bank=tid%32, free
        __syncthreads();

        const unsigned int rep = tid & 7u;
#pragma unroll
        for (int i = 0; i < EPT; i += 2) {
            unsigned int d0 = sc[i] >> 23;
            unsigned int d1 = sc[i + 1] >> 23;
            atomicAdd(&hist[9 * d0 + rep], 1u + (d0 == d1));
            if (d0 != d1) atomicAdd(&hist[9 * d1 + rep], 1u);
        }
        __syncthreads();

        unsigned int s = 0;                         // replica sum, stride-9 (free)
#pragma unroll
        for (int r = 0; r < 8; ++r) s += hist[9 * tid + r];
        bsum[tid] = s;
        __syncthreads();

        scan256(bsum, T, 23, kk);
        __syncthreads();
        T = bc[0]; kk = bc[1];
    }

    // =================== PASS 2: bits [22:15], 2 replicas ===================
    {
#pragma unroll
        for (int k = 0; k < 3; ++k) hist[tid + 256 * k] = 0;
        __syncthreads();

        const unsigned int rep = tid & 1u;
        const unsigned int hm = 0xFF800000u;        // bits [31:23] determined
#pragma unroll
        for (int i = 0; i < EPT; ++i) {
            if ((sc[i] & hm) == T)
                atomicAdd(&hist[3 * ((sc[i] >> 15) & 255u) + rep], 1u);
        }
        __syncthreads();

        bsum[tid] = hist[3 * tid] + hist[3 * tid + 1];
        __syncthreads();

        scan256(bsum, T, 15, kk);
        __syncthreads();
        T = bc[0]; kk = bc[1];
    }

    // =================== PASS 3: bits [14:7], no replicas ===================
    {
        hist[tid] = 0;
        __syncthreads();

        const unsigned int hm = 0xFFFF8000u;        // bits [31:15] determined
#pragma unroll
        for (int i = 0; i < EPT; ++i) {
            if ((sc[i] & hm) == T)
                atomicAdd(&hist[(sc[i] >> 7) & 255u], 1u);
        }
        __syncthreads();

        scan256(hist, T, 7, kk);
        __syncthreads();
        T = bc[0]; kk = bc[1];
    }

    // =================== PASS 4: bits [6:0], no replicas ====================
    {
        hist[tid] = 0;                              // bins 128..255 stay 0
        __syncthreads();

        const unsigned int hm = 0xFFFFFF80u;        // bits [31:7] determined
#pragma unroll
        for (int i = 0; i < EPT; ++i) {
            if ((sc[i] & hm) == T)
                atomicAdd(&hist[sc[i] & 127u], 1u);
        }
        __syncthreads();

        scan256(hist, T, 0, kk);
        __syncthreads();
        T = bc[0]; kk = bc[1];
    }

    // T = exact k-th largest key; kk = #(==T) to keep, lowest index first.
    unsigned int myeq = 0;
    bool isel[EPT];
#pragma unroll
    for (int i = 0; i < EPT; ++i) {
        isel[i] = sc[i] > T;
        myeq += (sc[i] == T) ? 1u : 0u;
    }
    tcnt[tid] = myeq;
    __syncthreads();

    // index-ordered exclusive scan of equal-counts (wave 0)
    if (tid < 64) {
        uint4 v = *(const uint4*)&tcnt[4 * tid];
        unsigned int tot = v.x + v.y + v.z + v.w;
        unsigned int S = tot;
#pragma unroll
        for (int off = 1; off < 64; off <<= 1) {
            unsigned int u = __shfl_up(S, off);
            if (tid >= off) S += u;
        }
        unsigned int excl = S - tot;
        uint4 o;
        o.x = excl;
        o.y = o.x + v.x;
        o.z = o.y + v.y;
        o.w = o.z + v.z;
        *(uint4*)&tcnt[4 * tid] = o;
    }
    __syncthreads();
    unsigned int ebase = tcnt[tid];

    float ov[EPT];
#pragma unroll
    for (int i = 0; i < EPT; ++i) {
        bool pick = isel[i];
        if (sc[i] == T) { pick = (ebase < kk); ebase += 1; }
        ov[i] = pick ? xv[i] : 0.0f;
    }
    *(float4*)(out + base)     = make_float4(ov[0], ov[1], ov[2], ov[3]);
    *(float4*)(out + base + 4) = make_float4(ov[4], ov[5], ov[6], ov[7]);
}

extern "C" void kernel_launch(void* const* d_in, const int* in_sizes, int n_in,
                              void* d_out, int out_size, void* d_ws, size_t ws_size,
                              hipStream_t stream)
{
    const float* x   = (const float*)d_in[0];
    const float* imp = (const float*)d_in[1];
    float* out       = (float*)d_out;

    const int rows = in_sizes[0] / COLS;   // 32768
    CompetitiveSelection_topk_kernel<<<dim3(rows), dim3(TPB), 0, stream>>>(x, imp, out);
}

// Round 3
// 104.740 us; speedup vs baseline: 1.5181x; 1.0356x over previous
//
#include <hip/hip_runtime.h>

#define COLS 2048
#define KSEL 256
#define TPB  256
#define EPT  8          // COLS / TPB

// One block per row. Exact top-K via radix select on score bit patterns
// (scores non-negative -> uint order monotone; bit31 = 0).
// P1: bits[30:23], 8 replica histograms (replica-major [8][260], odd stride).
// P2: bits[22:15], single histogram (active digits near-uniform).
// Then: if active set <= 64, compact + wave-0 ballot-radix on remaining bits
// (exact, no histograms). Full P3/P4 radix passes kept as fallback.
// Tie handling matches jax.lax.top_k (lower index first).
__global__ __launch_bounds__(TPB)
void CompetitiveSelection_topk_kernel(const float* __restrict__ x,
                                      const float* __restrict__ imp,
                                      float* __restrict__ out)
{
    const int row = blockIdx.x;
    const int tid = threadIdx.x;
    const long base = (long)row * COLS + (long)tid * EPT;

    __shared__ __align__(16) unsigned int hist[2080]; // P1 [8][260]; later passes use [0..255]
    __shared__ __align__(16) unsigned int bsum[256];  // P1 bin sums; small-path value buffer
    __shared__ unsigned int bc[4];                    // {T, kk, bin-count, compaction counter}

    // ---- load 8 contiguous x + importance values per thread ----
    float4 xa = *(const float4*)(x + base);
    float4 xb = *(const float4*)(x + base + 4);
    float4 ia = *(const float4*)(imp + tid * EPT);
    float4 ib = *(const float4*)(imp + tid * EPT + 4);

    float xv[EPT] = {xa.x, xa.y, xa.z, xa.w, xb.x, xb.y, xb.z, xb.w};
    float iv[EPT] = {ia.x, ia.y, ia.z, ia.w, ib.x, ib.y, ib.z, ib.w};

    unsigned int sc[EPT];
#pragma unroll
    for (int i = 0; i < EPT; ++i)
        sc[i] = __float_as_uint(fabsf(xv[i]) * fabsf(iv[i]));

    unsigned int T = 0, kk = KSEL, na = 0, ne = 0;

    // wave0: suffix-scan 256 counts, find bin containing rank curkk.
    // Publishes bc = {curT | c<<shift, rank-within-bin, bin count, 0}.
    auto scan256 = [&](const unsigned int* cnts, unsigned int curT, int shift,
                       unsigned int curkk) {
        if (tid < 64) {
            uint4 v4 = *(const uint4*)&cnts[4 * tid];
            unsigned int cnt[4] = {v4.x, v4.y, v4.z, v4.w};
            unsigned int tot = v4.x + v4.y + v4.z + v4.w;
            unsigned int S = tot;   // inclusive suffix sum over lanes >= tid
#pragma unroll
            for (int off = 1; off < 64; off <<= 1) {
                unsigned int u = __shfl_down(S, off);
                if (tid + off < 64) S += u;
            }
            unsigned int above = S - tot;   // count in bins >= 4*(tid+1)
            int c = -1; unsigned int cab = 0, cnb = 0;
#pragma unroll
            for (int b = 3; b >= 0; --b) {
                if (c < 0 && above < curkk && above + cnt[b] >= curkk) {
                    c = 4 * tid + b; cab = above; cnb = cnt[b];
                }
                above += cnt[b];
            }
            if (c >= 0) {   // exactly one lane
                bc[0] = curT | ((unsigned int)c << shift);
                bc[1] = curkk - cab;
                bc[2] = cnb;
                bc[3] = 0;
            }
        }
    };

    // =================== PASS 1: bits [30:23], 8 replicas ===================
    {
        uint4* H4 = (uint4*)hist;                 // vectorized clear of 2080 words
        H4[tid]       = make_uint4(0, 0, 0, 0);
        H4[256 + tid] = make_uint4(0, 0, 0, 0);
        if (tid < 8) H4[512 + tid] = make_uint4(0, 0, 0, 0);
        __syncthreads();

        const unsigned int rb = 260u * (tid & 7u);   // replica base, odd stride -> 8 banks/bin
#pragma unroll
        for (int g = 0; g < EPT; g += 4) {           // 4-way in-thread digit merge
            unsigned int d0 = sc[g] >> 23, d1 = sc[g + 1] >> 23,
                         d2 = sc[g + 2] >> 23, d3 = sc[g + 3] >> 23;
            atomicAdd(&hist[rb + d0], 1u + (d1 == d0) + (d2 == d0) + (d3 == d0));
            if (d1 != d0)                         atomicAdd(&hist[rb + d1], 1u + (d2 == d1) + (d3 == d1));
            if (d2 != d0 && d2 != d1)             atomicAdd(&hist[rb + d2], 1u + (d3 == d2));
            if (d3 != d0 && d3 != d1 && d3 != d2) atomicAdd(&hist[rb + d3], 1u);
        }
        __syncthreads();

        unsigned int s = 0;                        // replica sum, stride-260 (2-way, free)
#pragma unroll
        for (int r = 0; r < 8; ++r) s += hist[260 * r + tid];
        bsum[tid] = s;
        __syncthreads();

        scan256(bsum, 0u, 23, KSEL);
        __syncthreads();
        T = bc[0]; kk = bc[1]; na = bc[2];
    }

    int nbits = 23;
    unsigned int hm = 0xFF800000u;

    if (na > 64) {
        // =================== PASS 2: bits [22:15], single copy ===================
        hist[tid] = 0;
        __syncthreads();
#pragma unroll
        for (int i = 0; i < EPT; ++i)
            if ((sc[i] & hm) == T) atomicAdd(&hist[(sc[i] >> 15) & 255u], 1u);
        __syncthreads();
        scan256(hist, T, 15, kk);
        __syncthreads();
        T = bc[0]; kk = bc[1]; na = bc[2];
        nbits = 15; hm = 0xFFFF8000u;

        if (na > 64) {
            // =================== PASS 3 (fallback): bits [14:7] ===================
            hist[tid] = 0;
            __syncthreads();
#pragma unroll
            for (int i = 0; i < EPT; ++i)
                if ((sc[i] & hm) == T) atomicAdd(&hist[(sc[i] >> 7) & 255u], 1u);
            __syncthreads();
            scan256(hist, T, 7, kk);
            __syncthreads();
            T = bc[0]; kk = bc[1]; na = bc[2];
            nbits = 7; hm = 0xFFFFFF80u;

            if (na > 64) {
                // =================== PASS 4 (fallback): bits [6:0] ===================
                hist[tid] = 0;                     // bins 128..255 stay 0
                __syncthreads();
#pragma unroll
                for (int i = 0; i < EPT; ++i)
                    if ((sc[i] & hm) == T) atomicAdd(&hist[sc[i] & 127u], 1u);
                __syncthreads();
                scan256(hist, T, 0, kk);
                __syncthreads();
                T = bc[0]; kk = bc[1]; na = bc[2];
                nbits = 0;
            }
        }
    }

    if (nbits > 0) {
        // ---- small-set exact finish (na <= 64): compact values, ballot-radix ----
#pragma unroll
        for (int i = 0; i < EPT; ++i) {
            if ((sc[i] & hm) == T) {
                unsigned int p = atomicAdd(&bc[3], 1u);
                bsum[p] = sc[i];
            }
        }
        __syncthreads();
        if (tid < 64) {
            unsigned int v = (tid < (int)na) ? bsum[tid] : 0u;
            unsigned long long M = __ballot(tid < (int)na);
            unsigned int tl = 0, k2 = kk;
            for (int b = nbits - 1; b >= 0; --b) {
                unsigned long long ones = __ballot((v >> b) & 1u) & M;
                unsigned int c1 = (unsigned int)__popcll(ones);
                if (c1 >= k2) { M = ones; tl |= (1u << b); }
                else          { M &= ~ones; k2 -= c1; }
            }
            if (tid == 0) {
                bc[0] = T | tl;
                bc[1] = k2;                          // rank within equals
                bc[2] = (unsigned int)__popcll(M);   // ne = #equals
            }
        }
        __syncthreads();
        T = bc[0]; kk = bc[1]; ne = bc[2];
    } else {
        ne = na;   // after full pass 4, crossing-bin count == #equals
    }

    // ---- epilogue: T = exact k-th key; kk = #equals to keep (lowest index first) ----
    float ov[EPT];
    if (ne == kk) {
        // no boundary tie to split (common case): keep everything >= T
#pragma unroll
        for (int i = 0; i < EPT; ++i)
            ov[i] = (sc[i] >= T) ? xv[i] : 0.0f;
    } else {
        unsigned int myeq = 0;
        bool isel[EPT];
#pragma unroll
        for (int i = 0; i < EPT; ++i) {
            isel[i] = sc[i] > T;
            myeq += (sc[i] == T) ? 1u : 0u;
        }
        hist[tid] = myeq;                      // reuse hist as per-thread counts
        __syncthreads();
        if (tid < 64) {                        // index-ordered exclusive scan
            uint4 v = *(const uint4*)&hist[4 * tid];
            unsigned int tot = v.x + v.y + v.z + v.w;
            unsigned int S = tot;
#pragma unroll
            for (int off = 1; off < 64; off <<= 1) {
                unsigned int u = __shfl_up(S, off);
                if (tid >= off) S += u;
            }
            unsigned int excl = S - tot;
            uint4 o;
            o.x = excl; o.y = o.x + v.x; o.z = o.y + v.y; o.w = o.z + v.z;
            *(uint4*)&hist[4 * tid] = o;
        }
        __syncthreads();
        unsigned int ebase = hist[tid];
#pragma unroll
        for (int i = 0; i < EPT; ++i) {
            bool pick = isel[i];
            if (sc[i] == T) { pick = (ebase < kk); ebase += 1; }
            ov[i] = pick ? xv[i] : 0.0f;
        }
    }

    *(float4*)(out + base)     = make_float4(ov[0], ov[1], ov[2], ov[3]);
    *(float4*)(out + base + 4) = make_float4(ov[4], ov[5], ov[6], ov[7]);
}

extern "C" void kernel_launch(void* const* d_in, const int* in_sizes, int n_in,
                              void* d_out, int out_size, void* d_ws, size_t ws_size,
                              hipStream_t stream)
{
    const float* x   = (const float*)d_in[0];
    const float* imp = (const float*)d_in[1];
    float* out       = (float*)d_out;

    const int rows = in_sizes[0] / COLS;   // 32768
    CompetitiveSelection_topk_kernel<<<dim3(rows), dim3(TPB), 0, stream>>>(x, imp, out);
}